// Round 8
// baseline (203.460 us; speedup 1.0000x reference)
//
#include <hip/hip_runtime.h>

// E = sum over 4 directional diffs squared of avgpool4(mean_c(org - enhance)).
// R8: ONE stream per block. Kernel 1: block (r, a) reads a single contiguous
// 64 KB run (32 rows of one channel of ONE array, picked by blockIdx.y) via
// 16 nt loads/thread, pools 4x4, writes per-(array,channel) pooled maps
// pa[a][b*3+c][128][128] (12 MB ws). Tests the last lever: R0..R7 all
// interleaved org+enh streams in-wave and plateaued at ~3.5 TB/s read, while
// single-stream readers (m146) hit 4.9 TB/s. Kernel 2 fuses org-enh combine,
// channel sum, 1/48 scale and the 5-point stencil from L2-resident maps.

typedef float f4 __attribute__((ext_vector_type(4)));

__global__ __launch_bounds__(256) void pool_half_kernel(
    const f4* __restrict__ org, const f4* __restrict__ enh,
    float* __restrict__ pa) {
  __shared__ float red[8][128];
  int t = threadIdx.x;
  int r = blockIdx.x;                  // r = bc*16 + g ; bc = b*3+c, g = 32-row group
  int a = blockIdx.y;                  // 0 = org, 1 = enh
  int g  = r & 15;
  int bc = r >> 4;
  const f4* src = a ? enh : org;
  int base = bc * 65536 + g * 4096;    // float4 units; 64 KB contiguous run

  int px = t & 127;                    // pooled column (one float4 = 4 cols)
  int h  = t >> 7;                     // row parity within each 2-row chunk

  // 16 independent nt loads from ONE stream, issued up front.
  int j = base + t;
  f4 v0  = __builtin_nontemporal_load(&src[j +    0]);
  f4 v1  = __builtin_nontemporal_load(&src[j +  256]);
  f4 v2  = __builtin_nontemporal_load(&src[j +  512]);
  f4 v3  = __builtin_nontemporal_load(&src[j +  768]);
  f4 v4  = __builtin_nontemporal_load(&src[j + 1024]);
  f4 v5  = __builtin_nontemporal_load(&src[j + 1280]);
  f4 v6  = __builtin_nontemporal_load(&src[j + 1536]);
  f4 v7  = __builtin_nontemporal_load(&src[j + 1792]);
  f4 v8  = __builtin_nontemporal_load(&src[j + 2048]);
  f4 v9  = __builtin_nontemporal_load(&src[j + 2304]);
  f4 v10 = __builtin_nontemporal_load(&src[j + 2560]);
  f4 v11 = __builtin_nontemporal_load(&src[j + 2816]);
  f4 v12 = __builtin_nontemporal_load(&src[j + 3072]);
  f4 v13 = __builtin_nontemporal_load(&src[j + 3328]);
  f4 v14 = __builtin_nontemporal_load(&src[j + 3584]);
  f4 v15 = __builtin_nontemporal_load(&src[j + 3840]);

  // Pooled row pr <- chunks 2pr, 2pr+1 (this thread holds rows 4pr+h, 4pr+2+h).
  f4 s0 = v0  + v1;   f4 s1 = v2  + v3;
  f4 s2 = v4  + v5;   f4 s3 = v6  + v7;
  f4 s4 = v8  + v9;   f4 s5 = v10 + v11;
  f4 s6 = v12 + v13;  f4 s7 = v14 + v15;
  float p0 = s0.x + s0.y + s0.z + s0.w;
  float p1 = s1.x + s1.y + s1.z + s1.w;
  float p2 = s2.x + s2.y + s2.z + s2.w;
  float p3 = s3.x + s3.y + s3.z + s3.w;
  float p4 = s4.x + s4.y + s4.z + s4.w;
  float p5 = s5.x + s5.y + s5.z + s5.w;
  float p6 = s6.x + s6.y + s6.z + s6.w;
  float p7 = s7.x + s7.y + s7.z + s7.w;

  if (h == 1) {
    red[0][px] = p0; red[1][px] = p1; red[2][px] = p2; red[3][px] = p3;
    red[4][px] = p4; red[5][px] = p5; red[6][px] = p6; red[7][px] = p7;
  }
  __syncthreads();
  if (h == 0) {
    int ob = a * 1572864 + bc * 16384 + g * 8 * 128 + px;  // pa[a][bc][8 rows]
    pa[ob +   0] = p0 + red[0][px];
    pa[ob + 128] = p1 + red[1][px];
    pa[ob + 256] = p2 + red[2][px];
    pa[ob + 384] = p3 + red[3][px];
    pa[ob + 512] = p4 + red[4][px];
    pa[ob + 640] = p5 + red[5][px];
    pa[ob + 768] = p6 + red[6][px];
    pa[ob + 896] = p7 + red[7][px];
  }
}

__global__ __launch_bounds__(256) void combine_stencil_kernel(
    const float* __restrict__ pa, float* __restrict__ out) {
  int idx = blockIdx.x * 256 + threadIdx.x;   // = b*16384 + y*128 + x
  int x = idx & 127;
  int y = (idx >> 7) & 127;
  int b = idx >> 14;
  const float* o0 = pa + (b * 3 + 0) * 16384;           // org maps
  const float* o1 = pa + (b * 3 + 1) * 16384;
  const float* o2 = pa + (b * 3 + 2) * 16384;
  const float* e0 = o0 + 1572864;                        // enh maps
  const float* e1 = o1 + 1572864;
  const float* e2 = o2 + 1572864;
  int o = y * 128 + x;
  auto P = [&](int oo) {
    return ((o0[oo] + o1[oo] + o2[oo]) - (e0[oo] + e1[oo] + e2[oo])) * (1.0f / 48.0f);
  };
  float c = P(o);
  float l = (x > 0)   ? P(o - 1)   : 0.f;
  float r = (x < 127) ? P(o + 1)   : 0.f;
  float u = (y > 0)   ? P(o - 128) : 0.f;
  float d = (y < 127) ? P(o + 128) : 0.f;
  float dl = c - l, dr = c - r, du = c - u, dd = c - d;
  out[idx] = dl * dl + dr * dr + du * du + dd * dd;
}

extern "C" void kernel_launch(void* const* d_in, const int* in_sizes, int n_in,
                              void* d_out, int out_size, void* d_ws, size_t ws_size,
                              hipStream_t stream) {
  const f4* org = (const f4*)d_in[0];
  const f4* enh = (const f4*)d_in[1];
  float* pa  = (float*)d_ws;       // 2*96*128*128 floats = 12 MB scratch
  float* out = (float*)d_out;      // 32*1*128*128 floats

  dim3 grid1(32 * 3 * 16, 2);      // (bc*16 + g, array)
  pool_half_kernel<<<grid1, 256, 0, stream>>>(org, enh, pa);
  const int N = 32 * 128 * 128;
  combine_stencil_kernel<<<N / 256, 256, 0, stream>>>(pa, out);
}